// Round 1
// baseline (311.478 us; speedup 1.0000x reference)
//
#include <hip/hip_runtime.h>
#include <math.h>

#define NPTS 16384
#define NH   32
#define NC   128
#define NK   43

// ---------------- workspace layout (float indices) ----------------
enum : int {
  OFF_KP   = 0,        // 129 floats (pad to 256)
  OFF_W1T  = 256,      // 16384
  OFF_W3T  = 16640,    // 16384
  OFF_SC1  = 33024, OFF_SH1 = 33152,
  OFF_SC2  = 33280, OFF_SH2 = 33408,
  OFF_SC3  = 33536, OFF_SH3 = 33664,
  OFF_PART = 33792,    // 256*128*2 doubles = 131072 floats
  OFF_A    = 164864,   // N*C floats
  OFF_B    = 164864 + NPTS*NC,
};

// =================== kernel-point init (MT19937 replica) ===================
__device__ __forceinline__ unsigned int mt_temper(unsigned int y) {
  y ^= y >> 11;
  y ^= (y << 7)  & 0x9d2c5680u;
  y ^= (y << 15) & 0xefc60000u;
  y ^= y >> 18;
  return y;
}

__global__ void kp_init_kernel(float* __restrict__ kp) {
  __shared__ unsigned int mt[624];
  if (threadIdx.x != 0) return;

  mt[0] = 42u;
  for (int i = 1; i < 624; ++i)
    mt[i] = 1812433253u * (mt[i-1] ^ (mt[i-1] >> 30)) + (unsigned)i;
  int pos = 624;

  auto next = [&]() -> unsigned int {
    if (pos == 624) {
      for (int i = 0; i < 624; ++i) {
        unsigned int y = (mt[i] & 0x80000000u) | (mt[(i+1)%624] & 0x7fffffffu);
        unsigned int v = mt[(i+397)%624] ^ (y >> 1);
        if (y & 1u) v ^= 0x9908b0dfu;
        mt[i] = v;
      }
      pos = 0;
    }
    return mt_temper(mt[pos++]);
  };
  auto rdouble = [&]() -> double {
    unsigned int a = next() >> 5, b = next() >> 6;
    return ((double)a * 67108864.0 + (double)b) / 9007199254740992.0;
  };
  double gcache = 0.0; bool has_g = false;
  auto gauss = [&]() -> double {
    if (has_g) { has_g = false; return gcache; }
    double x1, x2, r2;
    do {
      x1 = 2.0 * rdouble() - 1.0;
      x2 = 2.0 * rdouble() - 1.0;
      r2 = x1*x1 + x2*x2;
    } while (r2 >= 1.0 || r2 == 0.0);
    double f = sqrt(-2.0 * log(r2) / r2);
    gcache = f * x1; has_g = true;
    return f * x2;
  };

  double g[126];
  for (int i = 0; i < 126; ++i) g[i] = gauss();

  kp[0] = 0.f; kp[1] = 0.f; kp[2] = 0.f;
  for (int r = 0; r < 14; ++r) {           // shell radius 0.5
    double x = g[r*3], y = g[r*3+1], z = g[r*3+2];
    double nrm = sqrt(x*x + y*y + z*z);
    kp[(1+r)*3+0] = (float)(x / nrm * 0.5);
    kp[(1+r)*3+1] = (float)(y / nrm * 0.5);
    kp[(1+r)*3+2] = (float)(z / nrm * 0.5);
  }
  for (int r = 0; r < 28; ++r) {           // shell radius 1.0
    double x = g[42+r*3], y = g[42+r*3+1], z = g[42+r*3+2];
    double nrm = sqrt(x*x + y*y + z*z);
    kp[(15+r)*3+0] = (float)(x / nrm);
    kp[(15+r)*3+1] = (float)(y / nrm);
    kp[(15+r)*3+2] = (float)(z / nrm);
  }
}

// =================== weight transpose (both fc mats) ===================
__global__ __launch_bounds__(256) void transpose_w(
    const float* __restrict__ w1, const float* __restrict__ w3,
    float* __restrict__ w1t, float* __restrict__ w3t) {
  int idx = blockIdx.x * 256 + threadIdx.x;       // 0..32767
  if (idx >= 2*NC*NC) return;
  int m = idx >> 14;
  int k = (idx >> 7) & 127;
  int c = idx & 127;
  const float* src = m ? w3 : w1;
  float* dst = m ? w3t : w1t;
  dst[k*NC + c] = src[c*NC + k];
}

// =================== GEMM: out[n][c] = sum_k A[n][k] * Wt[k][c] ===========
// 32-row tile, 256 threads, thread = (rowgroup g 0..7)x(col-quad lane 0..31)
__global__ __launch_bounds__(256) void gemm128(
    const float* __restrict__ A, const float* __restrict__ Wt,
    float* __restrict__ out) {
  __shared__ float a_s[32][NC];
  int row0 = blockIdx.x * 32;
  const float4* A4 = (const float4*)(A + (size_t)row0 * NC);
  float4* as4 = (float4*)&a_s[0][0];
  for (int i = threadIdx.x; i < 32 * 32; i += 256) as4[i] = A4[i];
  __syncthreads();

  int lane = threadIdx.x & 31;
  int g    = threadIdx.x >> 5;
  const float4* W4 = (const float4*)Wt;

  float4 acc[4];
  #pragma unroll
  for (int r = 0; r < 4; ++r) acc[r] = make_float4(0.f, 0.f, 0.f, 0.f);

  for (int k0 = 0; k0 < NC; k0 += 4) {
    float4 w0 = W4[(k0+0)*32 + lane];
    float4 w1 = W4[(k0+1)*32 + lane];
    float4 w2 = W4[(k0+2)*32 + lane];
    float4 w3 = W4[(k0+3)*32 + lane];
    #pragma unroll
    for (int r = 0; r < 4; ++r) {
      float4 a = *(const float4*)&a_s[g*4 + r][k0];
      acc[r].x = fmaf(a.x, w0.x, acc[r].x); acc[r].y = fmaf(a.x, w0.y, acc[r].y);
      acc[r].z = fmaf(a.x, w0.z, acc[r].z); acc[r].w = fmaf(a.x, w0.w, acc[r].w);
      acc[r].x = fmaf(a.y, w1.x, acc[r].x); acc[r].y = fmaf(a.y, w1.y, acc[r].y);
      acc[r].z = fmaf(a.y, w1.z, acc[r].z); acc[r].w = fmaf(a.y, w1.w, acc[r].w);
      acc[r].x = fmaf(a.z, w2.x, acc[r].x); acc[r].y = fmaf(a.z, w2.y, acc[r].y);
      acc[r].z = fmaf(a.z, w2.z, acc[r].z); acc[r].w = fmaf(a.z, w2.w, acc[r].w);
      acc[r].x = fmaf(a.w, w3.x, acc[r].x); acc[r].y = fmaf(a.w, w3.y, acc[r].y);
      acc[r].z = fmaf(a.w, w3.z, acc[r].z); acc[r].w = fmaf(a.w, w3.w, acc[r].w);
    }
  }
  #pragma unroll
  for (int r = 0; r < 4; ++r)
    ((float4*)(out + (size_t)(row0 + g*4 + r) * NC))[lane] = acc[r];
}

// =================== BN stats: 256 blocks x 64 rows, thread=channel ========
__global__ __launch_bounds__(128) void bn_stats(
    const float* __restrict__ x, double* __restrict__ part) {
  int c = threadIdx.x;
  int row0 = blockIdx.x * 64;
  double s = 0.0, s2 = 0.0;
  for (int r = 0; r < 64; ++r) {
    float v = x[(size_t)(row0 + r) * NC + c];
    s  += (double)v;
    s2 += (double)v * (double)v;
  }
  part[((size_t)blockIdx.x * NC + c) * 2 + 0] = s;
  part[((size_t)blockIdx.x * NC + c) * 2 + 1] = s2;
}

__global__ void bn_final(const double* __restrict__ part,
                         const float* __restrict__ g, const float* __restrict__ b,
                         float* __restrict__ sc, float* __restrict__ sh) {
  int c = threadIdx.x;
  double s = 0.0, s2 = 0.0;
  for (int i = 0; i < 256; ++i) {
    s  += part[((size_t)i * NC + c) * 2 + 0];
    s2 += part[((size_t)i * NC + c) * 2 + 1];
  }
  double mean = s * (1.0 / (double)NPTS);
  double var  = s2 * (1.0 / (double)NPTS) - mean * mean;
  double rstd = 1.0 / sqrt(var + 1e-5);
  double scale = (double)g[c] * rstd;
  sc[c] = (float)scale;
  sh[c] = (float)((double)b[c] - mean * scale);
}

__global__ __launch_bounds__(256) void bn_apply_relu(
    float* __restrict__ x, const float* __restrict__ sc, const float* __restrict__ sh) {
  int i = blockIdx.x * 256 + threadIdx.x;          // float4 index
  if (i >= NPTS * NC / 4) return;
  float4 v = ((const float4*)x)[i];
  int c = (i & 31) << 2;
  v.x = fmaxf(0.f, fmaf(v.x, sc[c+0], sh[c+0]));
  v.y = fmaxf(0.f, fmaf(v.y, sc[c+1], sh[c+1]));
  v.z = fmaxf(0.f, fmaf(v.z, sc[c+2], sh[c+2]));
  v.w = fmaxf(0.f, fmaf(v.w, sc[c+3], sh[c+3]));
  ((float4*)x)[i] = v;
}

// =================== KPConv (depthwise): 1 block = 1 point, 64 threads =====
__device__ __forceinline__ float readlane_f(float v, int lane) {
  return __uint_as_float((unsigned)__builtin_amdgcn_readlane((int)__float_as_uint(v), lane));
}

__global__ __launch_bounds__(64) void kpconv_kernel(
    const float* __restrict__ coord, const int* __restrict__ ref,
    const float* __restrict__ kp, const float* __restrict__ conv_w,
    const float* __restrict__ xr, float* __restrict__ y)
{
  int n = blockIdx.x;
  int l = threadIdx.x;                 // lane 0..63; channels 2l, 2l+1
  float kx = 0.f, ky = 0.f, kz = 0.f;
  if (l < NK) { kx = kp[l*3]; ky = kp[l*3+1]; kz = kp[l*3+2]; }
  float cx = coord[n*3+0], cy = coord[n*3+1], cz = coord[n*3+2];
  int refv = (l < NH) ? ref[(size_t)n * NH + l] : 0;

  const float2* cw2 = (const float2*)conv_w;
  const float2* xr2 = (const float2*)xr;
  float ax = 0.f, ay = 0.f;

  #pragma unroll 1
  for (int h = 0; h < NH; ++h) {
    int j = __builtin_amdgcn_readlane(refv, h);     // uniform
    bool shadow = ((unsigned)j >= (unsigned)NPTS);
    int js = shadow ? 0 : j;
    float px = (shadow ? 1e6f : coord[js*3+0]) - cx;
    float py = (shadow ? 1e6f : coord[js*3+1]) - cy;
    float pz = (shadow ? 1e6f : coord[js*3+2]) - cz;

    float dx = px - kx, dy = py - ky, dz = pz - kz;
    float infl = 1.f - sqrtf(fmaf(dx, dx, fmaf(dy, dy, dz*dz)));
    infl = (l < NK) ? fmaxf(infl, 0.f) : 0.f;

    unsigned long long m = __ballot(infl > 0.f);
    if (m != 0ull) {
      float wx = 0.f, wy = 0.f;
      do {
        int k = __builtin_ctzll(m);
        m &= (m - 1);
        float iv = readlane_f(infl, k);
        float2 cw = cw2[(size_t)k * 64 + l];
        wx = fmaf(iv, cw.x, wx);
        wy = fmaf(iv, cw.y, wy);
      } while (m != 0ull);
      float2 f = xr2[(size_t)j * 64 + l];
      ax = fmaf(wx, f.x, ax);
      ay = fmaf(wy, f.y, ay);
    }
  }
  float2 o; o.x = ax; o.y = ay;
  ((float2*)y)[(size_t)n * 64 + l] = o;
}

// =================== final: out = relu(identity + z*sc + sh) ================
__global__ __launch_bounds__(256) void final_out_kernel(
    const float* __restrict__ feat, const float* __restrict__ z,
    const float* __restrict__ sc, const float* __restrict__ sh,
    float* __restrict__ out) {
  int i = blockIdx.x * 256 + threadIdx.x;          // float4 index
  if (i >= NPTS * NC / 4) return;
  float4 f = ((const float4*)feat)[i];
  float4 v = ((const float4*)z)[i];
  int c = (i & 31) << 2;
  v.x = fmaxf(0.f, f.x + fmaf(v.x, sc[c+0], sh[c+0]));
  v.y = fmaxf(0.f, f.y + fmaf(v.y, sc[c+1], sh[c+1]));
  v.z = fmaxf(0.f, f.z + fmaf(v.z, sc[c+2], sh[c+2]));
  v.w = fmaxf(0.f, f.w + fmaf(v.w, sc[c+3], sh[c+3]));
  ((float4*)out)[NPTS*3/4 + i] = v;                // feat section starts at 49152 floats
}

__global__ void copy_coord_kernel(const float* __restrict__ coord,
                                  const int* __restrict__ offs,
                                  float* __restrict__ out) {
  int i = blockIdx.x * 256 + threadIdx.x;
  if (i < NPTS*3/4) ((float4*)out)[i] = ((const float4*)coord)[i];
  if (i == 0) out[NPTS*3 + (size_t)NPTS*NC] = (float)offs[0];   // offset as float
}

// =========================================================================
extern "C" void kernel_launch(void* const* d_in, const int* in_sizes, int n_in,
                              void* d_out, int out_size, void* d_ws, size_t ws_size,
                              hipStream_t stream) {
  (void)in_sizes; (void)n_in; (void)out_size; (void)ws_size;
  const float* coord = (const float*)d_in[0];
  const float* feat  = (const float*)d_in[1];
  const int*   offs  = (const int*)d_in[2];
  const int*   ref   = (const int*)d_in[3];
  const float* w1    = (const float*)d_in[4];
  const float* w3    = (const float*)d_in[5];
  const float* cw    = (const float*)d_in[6];
  const float* g1 = (const float*)d_in[7],  *b1 = (const float*)d_in[8];
  const float* g2 = (const float*)d_in[9],  *b2 = (const float*)d_in[10];
  const float* g3 = (const float*)d_in[11], *b3 = (const float*)d_in[12];

  float* ws  = (float*)d_ws;
  float* out = (float*)d_out;
  float* kp  = ws + OFF_KP;
  float* w1t = ws + OFF_W1T;
  float* w3t = ws + OFF_W3T;
  float* sc1 = ws + OFF_SC1, *sh1 = ws + OFF_SH1;
  float* sc2 = ws + OFF_SC2, *sh2 = ws + OFF_SH2;
  float* sc3 = ws + OFF_SC3, *sh3 = ws + OFF_SH3;
  double* part = (double*)(ws + OFF_PART);
  float* A = ws + OFF_A;     // x1 -> xr (in place) -> later z
  float* B = ws + OFF_B;     // y  -> yr (in place)

  kp_init_kernel<<<1, 64, 0, stream>>>(kp);
  transpose_w<<<128, 256, 0, stream>>>(w1, w3, w1t, w3t);

  // fc1 + BN1 + ReLU
  gemm128<<<NPTS/32, 256, 0, stream>>>(feat, w1t, A);
  bn_stats<<<256, 128, 0, stream>>>(A, part);
  bn_final<<<1, 128, 0, stream>>>(part, g1, b1, sc1, sh1);
  bn_apply_relu<<<NPTS*NC/4/256, 256, 0, stream>>>(A, sc1, sh1);

  // KPConv
  kpconv_kernel<<<NPTS, 64, 0, stream>>>(coord, ref, kp, cw, A, B);

  // BN2 + ReLU
  bn_stats<<<256, 128, 0, stream>>>(B, part);
  bn_final<<<1, 128, 0, stream>>>(part, g2, b2, sc2, sh2);
  bn_apply_relu<<<NPTS*NC/4/256, 256, 0, stream>>>(B, sc2, sh2);

  // fc3 + BN3
  gemm128<<<NPTS/32, 256, 0, stream>>>(B, w3t, A);
  bn_stats<<<256, 128, 0, stream>>>(A, part);
  bn_final<<<1, 128, 0, stream>>>(part, g3, b3, sc3, sh3);

  // residual + ReLU + outputs
  final_out_kernel<<<NPTS*NC/4/256, 256, 0, stream>>>(feat, A, sc3, sh3, out);
  copy_coord_kernel<<<48, 256, 0, stream>>>(coord, offs, out);
}

// Round 2
// 216.970 us; speedup vs baseline: 1.4356x; 1.4356x over previous
//
#include <hip/hip_runtime.h>
#include <math.h>

#define NPTS 16384
#define NH   32
#define NC   128
#define NK   43

// ---------------- workspace layout (float indices) ----------------
enum : int {
  OFF_W1T  = 256,      // 16384
  OFF_W3T  = 16640,    // 16384
  OFF_SC1  = 33024, OFF_SH1 = 33152,
  OFF_SC2  = 33280, OFF_SH2 = 33408,
  OFF_SC3  = 33536, OFF_SH3 = 33664,
  OFF_PART = 33792,    // 256*128*2 doubles = 131072 floats
  OFF_A    = 164864,   // N*C floats
  OFF_B    = 164864 + NPTS*NC,
};

struct KPArgs { float p[NK * 3]; };   // 516 B, passed by value (baked into graph)

// =================== host-side kernel-point computation ===================
// Exact replica of np.random.RandomState(42).randn + the shell construction.
static void host_make_kp(float* kp) {
  unsigned int mt[624];
  mt[0] = 42u;
  for (int i = 1; i < 624; ++i)
    mt[i] = 1812433253u * (mt[i-1] ^ (mt[i-1] >> 30)) + (unsigned)i;
  int pos = 624;
  auto next = [&]() -> unsigned int {
    if (pos == 624) {
      for (int i = 0; i < 624; ++i) {
        unsigned int y = (mt[i] & 0x80000000u) | (mt[(i+1)%624] & 0x7fffffffu);
        unsigned int v = mt[(i+397)%624] ^ (y >> 1);
        if (y & 1u) v ^= 0x9908b0dfu;
        mt[i] = v;
      }
      pos = 0;
    }
    unsigned int y = mt[pos++];
    y ^= y >> 11;
    y ^= (y << 7)  & 0x9d2c5680u;
    y ^= (y << 15) & 0xefc60000u;
    y ^= y >> 18;
    return y;
  };
  auto rdouble = [&]() -> double {
    unsigned int a = next() >> 5, b = next() >> 6;
    return ((double)a * 67108864.0 + (double)b) / 9007199254740992.0;
  };
  double gcache = 0.0; bool has_g = false;
  auto gauss = [&]() -> double {
    if (has_g) { has_g = false; return gcache; }
    double x1, x2, r2;
    do {
      x1 = 2.0 * rdouble() - 1.0;
      x2 = 2.0 * rdouble() - 1.0;
      r2 = x1*x1 + x2*x2;
    } while (r2 >= 1.0 || r2 == 0.0);
    double f = sqrt(-2.0 * log(r2) / r2);
    gcache = f * x1; has_g = true;
    return f * x2;
  };

  double g[126];
  for (int i = 0; i < 126; ++i) g[i] = gauss();

  kp[0] = 0.f; kp[1] = 0.f; kp[2] = 0.f;
  for (int r = 0; r < 14; ++r) {           // shell radius 0.5
    double x = g[r*3], y = g[r*3+1], z = g[r*3+2];
    double nrm = sqrt(x*x + y*y + z*z);
    kp[(1+r)*3+0] = (float)(x / nrm * 0.5);
    kp[(1+r)*3+1] = (float)(y / nrm * 0.5);
    kp[(1+r)*3+2] = (float)(z / nrm * 0.5);
  }
  for (int r = 0; r < 28; ++r) {           // shell radius 1.0
    double x = g[42+r*3], y = g[42+r*3+1], z = g[42+r*3+2];
    double nrm = sqrt(x*x + y*y + z*z);
    kp[(15+r)*3+0] = (float)(x / nrm);
    kp[(15+r)*3+1] = (float)(y / nrm);
    kp[(15+r)*3+2] = (float)(z / nrm);
  }
}

// =================== weight transpose (both fc mats) ===================
__global__ __launch_bounds__(256) void transpose_w(
    const float* __restrict__ w1, const float* __restrict__ w3,
    float* __restrict__ w1t, float* __restrict__ w3t) {
  int idx = blockIdx.x * 256 + threadIdx.x;       // 0..32767
  if (idx >= 2*NC*NC) return;
  int m = idx >> 14;
  int k = (idx >> 7) & 127;
  int c = idx & 127;
  const float* src = m ? w3 : w1;
  float* dst = m ? w3t : w1t;
  dst[k*NC + c] = src[c*NC + k];
}

// =================== GEMM: out[n][c] = sum_k A[n][k] * Wt[k][c] ===========
__global__ __launch_bounds__(256) void gemm128(
    const float* __restrict__ A, const float* __restrict__ Wt,
    float* __restrict__ out) {
  __shared__ float a_s[32][NC];
  int row0 = blockIdx.x * 32;
  const float4* A4 = (const float4*)(A + (size_t)row0 * NC);
  float4* as4 = (float4*)&a_s[0][0];
  for (int i = threadIdx.x; i < 32 * 32; i += 256) as4[i] = A4[i];
  __syncthreads();

  int lane = threadIdx.x & 31;
  int g    = threadIdx.x >> 5;
  const float4* W4 = (const float4*)Wt;

  float4 acc[4];
  #pragma unroll
  for (int r = 0; r < 4; ++r) acc[r] = make_float4(0.f, 0.f, 0.f, 0.f);

  for (int k0 = 0; k0 < NC; k0 += 4) {
    float4 w0 = W4[(k0+0)*32 + lane];
    float4 w1 = W4[(k0+1)*32 + lane];
    float4 w2 = W4[(k0+2)*32 + lane];
    float4 w3 = W4[(k0+3)*32 + lane];
    #pragma unroll
    for (int r = 0; r < 4; ++r) {
      float4 a = *(const float4*)&a_s[g*4 + r][k0];
      acc[r].x = fmaf(a.x, w0.x, acc[r].x); acc[r].y = fmaf(a.x, w0.y, acc[r].y);
      acc[r].z = fmaf(a.x, w0.z, acc[r].z); acc[r].w = fmaf(a.x, w0.w, acc[r].w);
      acc[r].x = fmaf(a.y, w1.x, acc[r].x); acc[r].y = fmaf(a.y, w1.y, acc[r].y);
      acc[r].z = fmaf(a.y, w1.z, acc[r].z); acc[r].w = fmaf(a.y, w1.w, acc[r].w);
      acc[r].x = fmaf(a.z, w2.x, acc[r].x); acc[r].y = fmaf(a.z, w2.y, acc[r].y);
      acc[r].z = fmaf(a.z, w2.z, acc[r].z); acc[r].w = fmaf(a.z, w2.w, acc[r].w);
      acc[r].x = fmaf(a.w, w3.x, acc[r].x); acc[r].y = fmaf(a.w, w3.y, acc[r].y);
      acc[r].z = fmaf(a.w, w3.z, acc[r].z); acc[r].w = fmaf(a.w, w3.w, acc[r].w);
    }
  }
  #pragma unroll
  for (int r = 0; r < 4; ++r)
    ((float4*)(out + (size_t)(row0 + g*4 + r) * NC))[lane] = acc[r];
}

// =================== BN stats ========
__global__ __launch_bounds__(128) void bn_stats(
    const float* __restrict__ x, double* __restrict__ part) {
  int c = threadIdx.x;
  int row0 = blockIdx.x * 64;
  double s = 0.0, s2 = 0.0;
  for (int r = 0; r < 64; ++r) {
    float v = x[(size_t)(row0 + r) * NC + c];
    s  += (double)v;
    s2 += (double)v * (double)v;
  }
  part[((size_t)blockIdx.x * NC + c) * 2 + 0] = s;
  part[((size_t)blockIdx.x * NC + c) * 2 + 1] = s2;
}

__global__ void bn_final(const double* __restrict__ part,
                         const float* __restrict__ g, const float* __restrict__ b,
                         float* __restrict__ sc, float* __restrict__ sh) {
  int c = threadIdx.x;
  double s = 0.0, s2 = 0.0;
  for (int i = 0; i < 256; ++i) {
    s  += part[((size_t)i * NC + c) * 2 + 0];
    s2 += part[((size_t)i * NC + c) * 2 + 1];
  }
  double mean = s * (1.0 / (double)NPTS);
  double var  = s2 * (1.0 / (double)NPTS) - mean * mean;
  double rstd = 1.0 / sqrt(var + 1e-5);
  double scale = (double)g[c] * rstd;
  sc[c] = (float)scale;
  sh[c] = (float)((double)b[c] - mean * scale);
}

__global__ __launch_bounds__(256) void bn_apply_relu(
    float* __restrict__ x, const float* __restrict__ sc, const float* __restrict__ sh) {
  int i = blockIdx.x * 256 + threadIdx.x;          // float4 index
  if (i >= NPTS * NC / 4) return;
  float4 v = ((const float4*)x)[i];
  int c = (i & 31) << 2;
  v.x = fmaxf(0.f, fmaf(v.x, sc[c+0], sh[c+0]));
  v.y = fmaxf(0.f, fmaf(v.y, sc[c+1], sh[c+1]));
  v.z = fmaxf(0.f, fmaf(v.z, sc[c+2], sh[c+2]));
  v.w = fmaxf(0.f, fmaf(v.w, sc[c+3], sh[c+3]));
  ((float4*)x)[i] = v;
}

// =================== KPConv (depthwise): 1 block = 1 point, 64 threads =====
__device__ __forceinline__ float readlane_f(float v, int lane) {
  return __uint_as_float((unsigned)__builtin_amdgcn_readlane((int)__float_as_uint(v), lane));
}

__global__ __launch_bounds__(64) void kpconv_kernel(
    const float* __restrict__ coord, const int* __restrict__ ref,
    const KPArgs kpa, const float* __restrict__ conv_w,
    const float* __restrict__ xr, float* __restrict__ y)
{
  int n = blockIdx.x;
  int l = threadIdx.x;                 // lane 0..63; channels 2l, 2l+1
  float kx = 0.f, ky = 0.f, kz = 0.f;
  if (l < NK) { kx = kpa.p[l*3]; ky = kpa.p[l*3+1]; kz = kpa.p[l*3+2]; }
  float cx = coord[n*3+0], cy = coord[n*3+1], cz = coord[n*3+2];
  int refv = (l < NH) ? ref[(size_t)n * NH + l] : 0;

  const float2* cw2 = (const float2*)conv_w;
  const float2* xr2 = (const float2*)xr;
  float ax = 0.f, ay = 0.f;

  #pragma unroll 1
  for (int h = 0; h < NH; ++h) {
    int j = __builtin_amdgcn_readlane(refv, h);     // uniform
    bool shadow = ((unsigned)j >= (unsigned)NPTS);
    int js = shadow ? 0 : j;
    float px = (shadow ? 1e6f : coord[js*3+0]) - cx;
    float py = (shadow ? 1e6f : coord[js*3+1]) - cy;
    float pz = (shadow ? 1e6f : coord[js*3+2]) - cz;

    float dx = px - kx, dy = py - ky, dz = pz - kz;
    float infl = 1.f - sqrtf(fmaf(dx, dx, fmaf(dy, dy, dz*dz)));
    infl = (l < NK) ? fmaxf(infl, 0.f) : 0.f;

    unsigned long long m = __ballot(infl > 0.f);
    if (m != 0ull) {
      float wx = 0.f, wy = 0.f;
      do {
        int k = __builtin_ctzll(m);
        m &= (m - 1);
        float iv = readlane_f(infl, k);
        float2 cw = cw2[(size_t)k * 64 + l];
        wx = fmaf(iv, cw.x, wx);
        wy = fmaf(iv, cw.y, wy);
      } while (m != 0ull);
      float2 f = xr2[(size_t)j * 64 + l];
      ax = fmaf(wx, f.x, ax);
      ay = fmaf(wy, f.y, ay);
    }
  }
  float2 o; o.x = ax; o.y = ay;
  ((float2*)y)[(size_t)n * 64 + l] = o;
}

// =================== final: out = relu(identity + z*sc + sh) ================
__global__ __launch_bounds__(256) void final_out_kernel(
    const float* __restrict__ feat, const float* __restrict__ z,
    const float* __restrict__ sc, const float* __restrict__ sh,
    float* __restrict__ out) {
  int i = blockIdx.x * 256 + threadIdx.x;          // float4 index
  if (i >= NPTS * NC / 4) return;
  float4 f = ((const float4*)feat)[i];
  float4 v = ((const float4*)z)[i];
  int c = (i & 31) << 2;
  v.x = fmaxf(0.f, f.x + fmaf(v.x, sc[c+0], sh[c+0]));
  v.y = fmaxf(0.f, f.y + fmaf(v.y, sc[c+1], sh[c+1]));
  v.z = fmaxf(0.f, f.z + fmaf(v.z, sc[c+2], sh[c+2]));
  v.w = fmaxf(0.f, f.w + fmaf(v.w, sc[c+3], sh[c+3]));
  ((float4*)out)[NPTS*3/4 + i] = v;
}

__global__ void copy_coord_kernel(const float* __restrict__ coord,
                                  const int* __restrict__ offs,
                                  float* __restrict__ out) {
  int i = blockIdx.x * 256 + threadIdx.x;
  if (i < NPTS*3/4) ((float4*)out)[i] = ((const float4*)coord)[i];
  if (i == 0) out[NPTS*3 + (size_t)NPTS*NC] = (float)offs[0];
}

// =========================================================================
extern "C" void kernel_launch(void* const* d_in, const int* in_sizes, int n_in,
                              void* d_out, int out_size, void* d_ws, size_t ws_size,
                              hipStream_t stream) {
  (void)in_sizes; (void)n_in; (void)out_size; (void)ws_size;
  const float* coord = (const float*)d_in[0];
  const float* feat  = (const float*)d_in[1];
  const int*   offs  = (const int*)d_in[2];
  const int*   ref   = (const int*)d_in[3];
  const float* w1    = (const float*)d_in[4];
  const float* w3    = (const float*)d_in[5];
  const float* cw    = (const float*)d_in[6];
  const float* g1 = (const float*)d_in[7],  *b1 = (const float*)d_in[8];
  const float* g2 = (const float*)d_in[9],  *b2 = (const float*)d_in[10];
  const float* g3 = (const float*)d_in[11], *b3 = (const float*)d_in[12];

  float* ws  = (float*)d_ws;
  float* out = (float*)d_out;
  float* w1t = ws + OFF_W1T;
  float* w3t = ws + OFF_W3T;
  float* sc1 = ws + OFF_SC1, *sh1 = ws + OFF_SH1;
  float* sc2 = ws + OFF_SC2, *sh2 = ws + OFF_SH2;
  float* sc3 = ws + OFF_SC3, *sh3 = ws + OFF_SH3;
  double* part = (double*)(ws + OFF_PART);
  float* A = ws + OFF_A;
  float* B = ws + OFF_B;

  KPArgs kpa;
  host_make_kp(kpa.p);                 // host-side, deterministic, baked into graph

  transpose_w<<<128, 256, 0, stream>>>(w1, w3, w1t, w3t);

  // fc1 + BN1 + ReLU
  gemm128<<<NPTS/32, 256, 0, stream>>>(feat, w1t, A);
  bn_stats<<<256, 128, 0, stream>>>(A, part);
  bn_final<<<1, 128, 0, stream>>>(part, g1, b1, sc1, sh1);
  bn_apply_relu<<<NPTS*NC/4/256, 256, 0, stream>>>(A, sc1, sh1);

  // KPConv
  kpconv_kernel<<<NPTS, 64, 0, stream>>>(coord, ref, kpa, cw, A, B);

  // BN2 + ReLU
  bn_stats<<<256, 128, 0, stream>>>(B, part);
  bn_final<<<1, 128, 0, stream>>>(part, g2, b2, sc2, sh2);
  bn_apply_relu<<<NPTS*NC/4/256, 256, 0, stream>>>(B, sc2, sh2);

  // fc3 + BN3
  gemm128<<<NPTS/32, 256, 0, stream>>>(B, w3t, A);
  bn_stats<<<256, 128, 0, stream>>>(A, part);
  bn_final<<<1, 128, 0, stream>>>(part, g3, b3, sc3, sh3);

  // residual + ReLU + outputs
  final_out_kernel<<<NPTS*NC/4/256, 256, 0, stream>>>(feat, A, sc3, sh3, out);
  copy_coord_kernel<<<48, 256, 0, stream>>>(coord, offs, out);
}

// Round 3
// 144.304 us; speedup vs baseline: 2.1585x; 1.5036x over previous
//
#include <hip/hip_runtime.h>
#include <math.h>

#define NPTS 16384
#define NH   32
#define NC   128
#define NK   43

typedef __attribute__((ext_vector_type(8))) short short8;
typedef __attribute__((ext_vector_type(4))) float f32x4;

// ---------------- workspace layout (float indices) ----------------
enum : int {
  OFF_W1T  = 0,         // 16384
  OFF_W3T  = 16384,     // 16384
  OFF_CWPK = 32768,     // 4096 floats (1024 x uint4): conv_w bf16 B-fragments
  OFF_KPF  = 36864,     // 256 (192 used): kernel points in A-frag k-order
  OFF_SC1  = 37120, OFF_SH1 = 37248,
  OFF_SC2  = 37376, OFF_SH2 = 37504,
  OFF_SC3  = 37632, OFF_SH3 = 37760,
  OFF_PART = 37888,     // 256*128*2 doubles = 131072 floats
  OFF_A    = 168960,    // N*C floats
  OFF_B    = 168960 + NPTS*NC,
};

struct KPArgs { float p[NK * 3]; };   // 516 B, computed on host, baked into graph

// =================== host-side kernel-point computation ===================
static void host_make_kp(float* kp) {
  unsigned int mt[624];
  mt[0] = 42u;
  for (int i = 1; i < 624; ++i)
    mt[i] = 1812433253u * (mt[i-1] ^ (mt[i-1] >> 30)) + (unsigned)i;
  int pos = 624;
  auto next = [&]() -> unsigned int {
    if (pos == 624) {
      for (int i = 0; i < 624; ++i) {
        unsigned int y = (mt[i] & 0x80000000u) | (mt[(i+1)%624] & 0x7fffffffu);
        unsigned int v = mt[(i+397)%624] ^ (y >> 1);
        if (y & 1u) v ^= 0x9908b0dfu;
        mt[i] = v;
      }
      pos = 0;
    }
    unsigned int y = mt[pos++];
    y ^= y >> 11;
    y ^= (y << 7)  & 0x9d2c5680u;
    y ^= (y << 15) & 0xefc60000u;
    y ^= y >> 18;
    return y;
  };
  auto rdouble = [&]() -> double {
    unsigned int a = next() >> 5, b = next() >> 6;
    return ((double)a * 67108864.0 + (double)b) / 9007199254740992.0;
  };
  double gcache = 0.0; bool has_g = false;
  auto gauss = [&]() -> double {
    if (has_g) { has_g = false; return gcache; }
    double x1, x2, r2;
    do {
      x1 = 2.0 * rdouble() - 1.0;
      x2 = 2.0 * rdouble() - 1.0;
      r2 = x1*x1 + x2*x2;
    } while (r2 >= 1.0 || r2 == 0.0);
    double f = sqrt(-2.0 * log(r2) / r2);
    gcache = f * x1; has_g = true;
    return f * x2;
  };
  double g[126];
  for (int i = 0; i < 126; ++i) g[i] = gauss();
  kp[0] = 0.f; kp[1] = 0.f; kp[2] = 0.f;
  for (int r = 0; r < 14; ++r) {
    double x = g[r*3], y = g[r*3+1], z = g[r*3+2];
    double nrm = sqrt(x*x + y*y + z*z);
    kp[(1+r)*3+0] = (float)(x / nrm * 0.5);
    kp[(1+r)*3+1] = (float)(y / nrm * 0.5);
    kp[(1+r)*3+2] = (float)(z / nrm * 0.5);
  }
  for (int r = 0; r < 28; ++r) {
    double x = g[42+r*3], y = g[42+r*3+1], z = g[42+r*3+2];
    double nrm = sqrt(x*x + y*y + z*z);
    kp[(15+r)*3+0] = (float)(x / nrm);
    kp[(15+r)*3+1] = (float)(y / nrm);
    kp[(15+r)*3+2] = (float)(z / nrm);
  }
}

__device__ __forceinline__ unsigned short f2bf(float f) {
  unsigned u = __float_as_uint(f);
  return (unsigned short)((u + 0x7FFFu + ((u >> 16) & 1u)) >> 16);
}

// =================== prep: W transposes + conv_w B-frags + kp A-order =====
__global__ __launch_bounds__(256) void prep_kernel(
    const float* __restrict__ w1, const float* __restrict__ w3,
    const float* __restrict__ cw, KPArgs kpa,
    float* __restrict__ w1t, float* __restrict__ w3t,
    uint4* __restrict__ cwpk, float* __restrict__ kpf) {
  int idx = blockIdx.x * 256 + threadIdx.x;
  if (idx < 2*NC*NC) {
    int m = idx >> 14, k = (idx >> 7) & 127, c = idx & 127;
    (m ? w3t : w1t)[k*NC + c] = (m ? w3 : w1)[c*NC + k];
  } else if (idx < 2*NC*NC + 1024) {
    // B-fragment pack: frag f = ks*8+nt, lane l: col c=nt*16+(l&15), k=ks*32+(l>>4)*8+i
    int t = idx - 2*NC*NC;
    int f = t >> 6, l = t & 63;
    int ks = f >> 3, nt = f & 7, g = l >> 4, li = l & 15;
    int c = nt*16 + li, k0 = ks*32 + g*8;
    float v[8];
    #pragma unroll
    for (int i = 0; i < 8; ++i) {
      int k = k0 + i;
      v[i] = (k < NK) ? cw[k*NC + c] : 0.f;
    }
    uint4 q;
    q.x = (unsigned)f2bf(v[0]) | ((unsigned)f2bf(v[1]) << 16);
    q.y = (unsigned)f2bf(v[2]) | ((unsigned)f2bf(v[3]) << 16);
    q.z = (unsigned)f2bf(v[4]) | ((unsigned)f2bf(v[5]) << 16);
    q.w = (unsigned)f2bf(v[6]) | ((unsigned)f2bf(v[7]) << 16);
    cwpk[f*64 + l] = q;
  } else if (idx < 2*NC*NC + 1024 + 192) {
    // kp in A-frag order: kpf[comp*64 + ks*32 + g*8 + i]; padded k -> 1e9 (infl==0)
    int t = idx - (2*NC*NC + 1024);
    int comp = t >> 6, slot = t & 63;
    int ks = slot >> 5, g = (slot >> 3) & 3, i = slot & 7;
    int k = ks*32 + g*8 + i;
    kpf[comp*64 + slot] = (k < NK) ? kpa.p[k*3 + comp] : 1e9f;
  }
}

// =================== GEMM: out[n][c] = sum_k in[n][k] * Wt[k][c] ==========
// BN==1: apply relu(in*sc+sh) while staging into LDS (fuses BN2-apply)
template<int BN>
__global__ __launch_bounds__(256) void gemm128(
    const float* __restrict__ A, const float* __restrict__ Wt,
    const float* __restrict__ sc, const float* __restrict__ sh,
    float* __restrict__ out) {
  __shared__ float a_s[32][NC];
  int row0 = blockIdx.x * 32;
  const float4* A4 = (const float4*)(A + (size_t)row0 * NC);
  float4* as4 = (float4*)&a_s[0][0];
  if (BN) {
    int c4 = (threadIdx.x & 31) << 2;
    float4 s = *(const float4*)(sc + c4);
    float4 h = *(const float4*)(sh + c4);
    for (int i = threadIdx.x; i < 32 * 32; i += 256) {
      float4 v = A4[i];
      v.x = fmaxf(0.f, fmaf(v.x, s.x, h.x));
      v.y = fmaxf(0.f, fmaf(v.y, s.y, h.y));
      v.z = fmaxf(0.f, fmaf(v.z, s.z, h.z));
      v.w = fmaxf(0.f, fmaf(v.w, s.w, h.w));
      as4[i] = v;
    }
  } else {
    for (int i = threadIdx.x; i < 32 * 32; i += 256) as4[i] = A4[i];
  }
  __syncthreads();

  int lane = threadIdx.x & 31;
  int g    = threadIdx.x >> 5;
  const float4* W4 = (const float4*)Wt;

  float4 acc[4];
  #pragma unroll
  for (int r = 0; r < 4; ++r) acc[r] = make_float4(0.f, 0.f, 0.f, 0.f);

  for (int k0 = 0; k0 < NC; k0 += 4) {
    float4 w0 = W4[(k0+0)*32 + lane];
    float4 w1 = W4[(k0+1)*32 + lane];
    float4 w2 = W4[(k0+2)*32 + lane];
    float4 w3 = W4[(k0+3)*32 + lane];
    #pragma unroll
    for (int r = 0; r < 4; ++r) {
      float4 a = *(const float4*)&a_s[g*4 + r][k0];
      acc[r].x = fmaf(a.x, w0.x, acc[r].x); acc[r].y = fmaf(a.x, w0.y, acc[r].y);
      acc[r].z = fmaf(a.x, w0.z, acc[r].z); acc[r].w = fmaf(a.x, w0.w, acc[r].w);
      acc[r].x = fmaf(a.y, w1.x, acc[r].x); acc[r].y = fmaf(a.y, w1.y, acc[r].y);
      acc[r].z = fmaf(a.y, w1.z, acc[r].z); acc[r].w = fmaf(a.y, w1.w, acc[r].w);
      acc[r].x = fmaf(a.z, w2.x, acc[r].x); acc[r].y = fmaf(a.z, w2.y, acc[r].y);
      acc[r].z = fmaf(a.z, w2.z, acc[r].z); acc[r].w = fmaf(a.z, w2.w, acc[r].w);
      acc[r].x = fmaf(a.w, w3.x, acc[r].x); acc[r].y = fmaf(a.w, w3.y, acc[r].y);
      acc[r].z = fmaf(a.w, w3.z, acc[r].z); acc[r].w = fmaf(a.w, w3.w, acc[r].w);
    }
  }
  #pragma unroll
  for (int r = 0; r < 4; ++r)
    ((float4*)(out + (size_t)(row0 + g*4 + r) * NC))[lane] = acc[r];
}

// =================== BN stats / final ========
__global__ __launch_bounds__(128) void bn_stats(
    const float* __restrict__ x, double* __restrict__ part) {
  int c = threadIdx.x;
  int row0 = blockIdx.x * 64;
  double s = 0.0, s2 = 0.0;
  for (int r = 0; r < 64; ++r) {
    float v = x[(size_t)(row0 + r) * NC + c];
    s  += (double)v;
    s2 += (double)v * (double)v;
  }
  part[((size_t)blockIdx.x * NC + c) * 2 + 0] = s;
  part[((size_t)blockIdx.x * NC + c) * 2 + 1] = s2;
}

__global__ void bn_final(const double* __restrict__ part,
                         const float* __restrict__ g, const float* __restrict__ b,
                         float* __restrict__ sc, float* __restrict__ sh) {
  int c = threadIdx.x;
  double s = 0.0, s2 = 0.0;
  for (int i = 0; i < 256; ++i) {
    s  += part[((size_t)i * NC + c) * 2 + 0];
    s2 += part[((size_t)i * NC + c) * 2 + 1];
  }
  double mean = s * (1.0 / (double)NPTS);
  double var  = s2 * (1.0 / (double)NPTS) - mean * mean;
  double rstd = 1.0 / sqrt(var + 1e-5);
  double scale = (double)g[c] * rstd;
  sc[c] = (float)scale;
  sh[c] = (float)((double)b[c] - mean * scale);
}

// =================== KPConv via MFMA: s = infl @ conv_w, out = sum_h s.*feat
// 1 wave per point (4 waves / 256-thr block). BN1-apply+ReLU fused on gather.
__global__ __launch_bounds__(256) void kpconv_kernel(
    const float* __restrict__ coord, const int* __restrict__ ref,
    const float* __restrict__ xr, const uint4* __restrict__ cwpk,
    const float* __restrict__ kpf,
    const float* __restrict__ sc1, const float* __restrict__ sh1,
    float* __restrict__ y)
{
  int l  = threadIdx.x & 63;
  int n  = blockIdx.x * 4 + (threadIdx.x >> 6);
  int g  = l >> 4, li = l & 15;

  float cx = coord[n*3+0], cy = coord[n*3+1], cz = coord[n*3+2];
  int j = ref[(size_t)n * NH + (l & 31)];
  bool shadow = ((unsigned)j >= (unsigned)NPTS);
  int jc = shadow ? 0 : j;
  float qx = shadow ? 1e6f : coord[jc*3+0];
  float qy = shadow ? 1e6f : coord[jc*3+1];
  float qz = shadow ? 1e6f : coord[jc*3+2];
  float px = qx - cx, py = qy - cy, pz = qz - cz;

  // neighbor positions for this lane's two A-tile rows (h=li and h=li+16)
  float p0x = __shfl(px, li),      p0y = __shfl(py, li),      p0z = __shfl(pz, li);
  float p1x = __shfl(px, li + 16), p1y = __shfl(py, li + 16), p1z = __shfl(pz, li + 16);

  // A fragments: infl[h][k] in bf16, lane covers k = ks*32 + g*8 + i
  short8 afr[2][2];   // [mt][ks]
  #pragma unroll
  for (int ks = 0; ks < 2; ++ks) {
    const float4* kbx = (const float4*)(kpf +   0 + (ks*4+g)*8);
    const float4* kby = (const float4*)(kpf +  64 + (ks*4+g)*8);
    const float4* kbz = (const float4*)(kpf + 128 + (ks*4+g)*8);
    float4 x0 = kbx[0], x1 = kbx[1];
    float4 y0 = kby[0], y1 = kby[1];
    float4 z0 = kbz[0], z1 = kbz[1];
    float kx[8] = {x0.x,x0.y,x0.z,x0.w,x1.x,x1.y,x1.z,x1.w};
    float ky[8] = {y0.x,y0.y,y0.z,y0.w,y1.x,y1.y,y1.z,y1.w};
    float kz[8] = {z0.x,z0.y,z0.z,z0.w,z1.x,z1.y,z1.z,z1.w};
    #pragma unroll
    for (int mt = 0; mt < 2; ++mt) {
      float fx = mt ? p1x : p0x, fy = mt ? p1y : p0y, fz = mt ? p1z : p0z;
      short8 af;
      #pragma unroll
      for (int i = 0; i < 8; ++i) {
        float dx = fx - kx[i], dy = fy - ky[i], dz = fz - kz[i];
        float d2 = fmaf(dx, dx, fmaf(dy, dy, dz*dz));
        float iv = fmaxf(1.f - sqrtf(d2), 0.f);
        af[i] = (short)f2bf(iv);
      }
      afr[mt][ks] = af;
    }
  }

  // s[mt][nt] = infl @ conv_w  (B-frags loaded lazily, L2-hot 16KB)
  f32x4 acc[2][8];
  #pragma unroll
  for (int mt = 0; mt < 2; ++mt)
    #pragma unroll
    for (int nt = 0; nt < 8; ++nt)
      acc[mt][nt] = (f32x4){0.f, 0.f, 0.f, 0.f};

  #pragma unroll
  for (int nt = 0; nt < 8; ++nt) {
    uint4 b0 = cwpk[(0*8 + nt)*64 + l];
    uint4 b1 = cwpk[(1*8 + nt)*64 + l];
    union { uint4 u; short8 s; } c0, c1;
    c0.u = b0; c1.u = b1;
    #pragma unroll
    for (int mt = 0; mt < 2; ++mt) {
      acc[mt][nt] = __builtin_amdgcn_mfma_f32_16x16x32_bf16(afr[mt][0], c0.s, acc[mt][nt], 0, 0, 0);
      acc[mt][nt] = __builtin_amdgcn_mfma_f32_16x16x32_bf16(afr[mt][1], c1.s, acc[mt][nt], 0, 0, 0);
    }
  }

  // BN1 scale/shift for this lane's 8 columns (c = nt*16+li)
  float s1[8], h1[8];
  #pragma unroll
  for (int nt = 0; nt < 8; ++nt) { s1[nt] = sc1[nt*16 + li]; h1[nt] = sh1[nt*16 + li]; }

  // apply: out[c] = sum_h s[h][c] * relu(bn1(xr[j(h)][c]))
  float outp[8];
  #pragma unroll
  for (int nt = 0; nt < 8; ++nt) outp[nt] = 0.f;

  #pragma unroll
  for (int mt = 0; mt < 2; ++mt) {
    #pragma unroll
    for (int r = 0; r < 4; ++r) {
      int h = mt*16 + g*4 + r;
      int jh = __shfl(j, h);
      int jhc = ((unsigned)jh >= (unsigned)NPTS) ? 0 : jh;
      const float* row = xr + (size_t)jhc * NC;
      #pragma unroll
      for (int nt = 0; nt < 8; ++nt) {
        float fv = row[nt*16 + li];
        fv = fmaxf(0.f, fmaf(fv, s1[nt], h1[nt]));
        outp[nt] = fmaf(acc[mt][nt][r], fv, outp[nt]);
      }
    }
  }

  // reduce over the 4 lane-groups (rows were split across l>>4)
  #pragma unroll
  for (int nt = 0; nt < 8; ++nt) {
    outp[nt] += __shfl_xor(outp[nt], 16);
    outp[nt] += __shfl_xor(outp[nt], 32);
  }
  // lane l writes c=l (nt=g) and c=64+l (nt=4+g); avoid dynamic reg indexing
  float o0 = (g == 0) ? outp[0] : (g == 1) ? outp[1] : (g == 2) ? outp[2] : outp[3];
  float o1 = (g == 0) ? outp[4] : (g == 1) ? outp[5] : (g == 2) ? outp[6] : outp[7];
  y[(size_t)n * NC + l]      = o0;
  y[(size_t)n * NC + 64 + l] = o1;
}

// =================== final: out = relu(identity + z*sc + sh) + coord/offset =
__global__ __launch_bounds__(256) void final_out_kernel(
    const float* __restrict__ feat, const float* __restrict__ z,
    const float* __restrict__ sc, const float* __restrict__ sh,
    const float* __restrict__ coord, const int* __restrict__ offs,
    float* __restrict__ out) {
  int i = blockIdx.x * 256 + threadIdx.x;
  if (i < NPTS * NC / 4) {
    float4 f = ((const float4*)feat)[i];
    float4 v = ((const float4*)z)[i];
    int c = (i & 31) << 2;
    v.x = fmaxf(0.f, f.x + fmaf(v.x, sc[c+0], sh[c+0]));
    v.y = fmaxf(0.f, f.y + fmaf(v.y, sc[c+1], sh[c+1]));
    v.z = fmaxf(0.f, f.z + fmaf(v.z, sc[c+2], sh[c+2]));
    v.w = fmaxf(0.f, f.w + fmaf(v.w, sc[c+3], sh[c+3]));
    ((float4*)out)[NPTS*3/4 + i] = v;
  } else {
    int ci = i - NPTS * NC / 4;
    if (ci < NPTS*3/4) ((float4*)out)[ci] = ((const float4*)coord)[ci];
    if (ci == 0) out[NPTS*3 + (size_t)NPTS*NC] = (float)offs[0];
  }
}

// =========================================================================
extern "C" void kernel_launch(void* const* d_in, const int* in_sizes, int n_in,
                              void* d_out, int out_size, void* d_ws, size_t ws_size,
                              hipStream_t stream) {
  (void)in_sizes; (void)n_in; (void)out_size; (void)ws_size;
  const float* coord = (const float*)d_in[0];
  const float* feat  = (const float*)d_in[1];
  const int*   offs  = (const int*)d_in[2];
  const int*   ref   = (const int*)d_in[3];
  const float* w1    = (const float*)d_in[4];
  const float* w3    = (const float*)d_in[5];
  const float* cw    = (const float*)d_in[6];
  const float* g1 = (const float*)d_in[7],  *b1 = (const float*)d_in[8];
  const float* g2 = (const float*)d_in[9],  *b2 = (const float*)d_in[10];
  const float* g3 = (const float*)d_in[11], *b3 = (const float*)d_in[12];

  float* ws  = (float*)d_ws;
  float* out = (float*)d_out;
  float* w1t = ws + OFF_W1T;
  float* w3t = ws + OFF_W3T;
  uint4* cwpk = (uint4*)(ws + OFF_CWPK);
  float* kpf = ws + OFF_KPF;
  float* sc1 = ws + OFF_SC1, *sh1 = ws + OFF_SH1;
  float* sc2 = ws + OFF_SC2, *sh2 = ws + OFF_SH2;
  float* sc3 = ws + OFF_SC3, *sh3 = ws + OFF_SH3;
  double* part = (double*)(ws + OFF_PART);
  float* A = ws + OFF_A;
  float* B = ws + OFF_B;

  KPArgs kpa;
  host_make_kp(kpa.p);

  prep_kernel<<<133, 256, 0, stream>>>(w1, w3, cw, kpa, w1t, w3t, cwpk, kpf);

  // fc1 (raw) -> stats -> finalize (apply fused into kpconv gather)
  gemm128<0><<<NPTS/32, 256, 0, stream>>>(feat, w1t, nullptr, nullptr, A);
  bn_stats<<<256, 128, 0, stream>>>(A, part);
  bn_final<<<1, 128, 0, stream>>>(part, g1, b1, sc1, sh1);

  // KPConv (MFMA) with fused BN1-apply+ReLU
  kpconv_kernel<<<NPTS/4, 256, 0, stream>>>(coord, ref, A, cwpk, kpf, sc1, sh1, B);

  // BN2 stats -> finalize (apply fused into fc3 LDS stage)
  bn_stats<<<256, 128, 0, stream>>>(B, part);
  bn_final<<<1, 128, 0, stream>>>(part, g2, b2, sc2, sh2);

  // fc3 with fused BN2-apply+ReLU -> stats -> finalize
  gemm128<1><<<NPTS/32, 256, 0, stream>>>(B, w3t, sc2, sh2, A);
  bn_stats<<<256, 128, 0, stream>>>(A, part);
  bn_final<<<1, 128, 0, stream>>>(part, g3, b3, sc3, sh3);

  // residual + ReLU + coord + offset
  final_out_kernel<<<(NPTS*NC/4 + NPTS*3/4 + 255)/256, 256, 0, stream>>>(
      feat, A, sc3, sh3, coord, offs, out);
}